// Round 6
// baseline (153.421 us; speedup 1.0000x reference)
//
#include <hip/hip_runtime.h>

// Trilinear warp (SpatialTransformer): vol [B=2,D=160,H=192,W=160,C=2] f32,
// flow [B,D,H,W,3] f32 ('ij'). Output f32, same shape as vol.
//
// R5 lesson: limiter is L2 gather-request RATE (~39M line requests ~= 127us),
// not HBM bytes (FETCH=219MB ~= 1.1x ideal) and not gather instruction count
// (z-fusion was null). Fix: stage tile+halo vol region in LDS so each L2 line
// is requested once per block; serve the 8 corner reads from LDS.
// Rare |flow|>=4 samples (P~6e-5) take an exec-masked exact global fallback.

constexpr int Bb = 2;
constexpr int Dd = 160;
constexpr int Hh = 192;
constexpr int Ww = 160;
constexpr int HW  = Hh * Ww;          // 30720
constexpr int VOX = Dd * HW;          // 4,915,200 voxels per batch

constexpr int TD = 8,  TH = 16, TW = 16;   // output tile per block (2048 voxels)
constexpr int RD = TD + 8;                 // 16  staged region (halo 4 each side)
constexpr int RH = TH + 8;                 // 24
constexpr int RW = TW + 8;                 // 24  (always even, incl. edges)
constexpr int RWP = 26;                    // padded LDS row stride (float2 units)
constexpr int QROW = RW / 2;               // 12 float4 quads per staged row
constexpr int ND = Dd / TD, NH = Hh / TH, NW = Ww / TW;   // 20, 12, 10
constexpr int NBLK = Bb * ND * NH * NW;                   // 4800
constexpr size_t LDS_BYTES = (size_t)RD * RH * RWP * sizeof(float2);  // 79872 B

__global__ __launch_bounds__(256)
void SpatialTransformer_44418551776013_kernel(const float* __restrict__ vol,
                                              const float* __restrict__ flow,
                                              float* __restrict__ out)
{
    extern __shared__ float2 sv[];   // [RD][RH][RWP]
    const int tid = threadIdx.x;

    int bid = blockIdx.x;
    const int bw = bid % NW;  bid /= NW;
    const int bh = bid % NH;  bid /= NH;
    const int bd = bid % ND;
    const int b  = bid / ND;

    const int d0 = bd * TD, h0 = bh * TH, w0 = bw * TW;

    // staged region = clip(tile +- 4) to volume. All clamped in-halo sample
    // indices provably land inside this region (see in-region test below).
    const int ox = max(0, d0 - 4);
    const int oy = max(0, h0 - 4);
    const int oz = max(0, w0 - 4);
    const int ex = min(Dd - 1, d0 + TD - 1 + 4) - ox + 1;   // <= RD
    const int ey = min(Hh - 1, h0 + TH - 1 + 4) - oy + 1;   // <= RH
    const int ez = min(Ww - 1, w0 + TW - 1 + 4) - oz + 1;   // <= RW, always even
    const int qz = ez >> 1;

    const float2* __restrict__ v2 =
        reinterpret_cast<const float2*>(vol) + (size_t)b * VOX;

    // ---- stage region into LDS: coalesced float4 (2 voxels) per lane ----
    // oz is always even and HW, Ww are even -> global float4 reads 16B-aligned.
    // LDS index (row*RWP + 2*lq) is even -> 16B-aligned ds_write_b128.
    #pragma unroll 1
    for (int i = tid; i < RD * RH * QROW; i += 256) {   // 18 iterations
        const int lq = i % QROW;            // compile-time divisors -> magic mul
        const int t  = i / QROW;
        const int ly = t % RH;
        const int lx = t / RH;
        if (lx < ex && ly < ey && lq < qz) {
            const float4 v = *reinterpret_cast<const float4*>(
                v2 + ((size_t)(ox + lx) * HW + (oy + ly) * Ww + oz + 2 * lq));
            *reinterpret_cast<float4*>(&sv[(lx * RH + ly) * RWP + 2 * lq]) = v;
        }
    }
    __syncthreads();

    // ---- process tile: thread = (th, tw), loop over td ----
    const int tw = tid & 15;
    const int th = tid >> 4;
    const int h = h0 + th;
    const int w = w0 + tw;

    const float mx = (float)(Dd - 1), my = (float)(Hh - 1), mz = (float)(Ww - 1);

    int gidx = ((b * Dd + d0) * Hh + h) * Ww + w;
    // prefetch flow for td = 0
    float fx = flow[(size_t)gidx * 3 + 0];
    float fy = flow[(size_t)gidx * 3 + 1];
    float fz = flow[(size_t)gidx * 3 + 2];

    #pragma unroll 1
    for (int td = 0; td < TD; ++td) {
        const int d = d0 + td;
        const int gcur = gidx;

        // prefetch next td's flow (hides latency under this iteration's work)
        float nfx = 0.f, nfy = 0.f, nfz = 0.f;
        if (td + 1 < TD) {
            const size_t gn = (size_t)(gidx + HW) * 3;
            nfx = flow[gn + 0];  nfy = flow[gn + 1];  nfz = flow[gn + 2];
        }

        // ---- exact reference math ----
        const float lxf = (float)d + fx;
        const float lyf = (float)h + fy;
        const float lzf = (float)w + fz;

        const float l0x = fminf(fmaxf(floorf(lxf), 0.0f), mx);
        const float l0y = fminf(fmaxf(floorf(lyf), 0.0f), my);
        const float l0z = fminf(fmaxf(floorf(lzf), 0.0f), mz);
        const float l1x = fminf(l0x + 1.0f, mx);
        const float l1y = fminf(l0y + 1.0f, my);
        const float l1z = fminf(l0z + 1.0f, mz);

        const float d1x = l1x - lxf, d0x = 1.0f - d1x;
        const float d1y = l1y - lyf, d0y = 1.0f - d1y;
        const float d1z = l1z - lzf, d0z = 1.0f - d1z;

        const int i0x = (int)l0x, i1x = (int)l1x;
        const int i0y = (int)l0y, i1y = (int)l1y;
        const int i0z = (int)l0z, i1z = (int)l1z;

        // region-local coordinates; in-region iff all in [0, ext)
        const int a0x = i0x - ox, a1x = i1x - ox;
        const int a0y = i0y - oy, a1y = i1y - oy;
        const int a0z = i0z - oz, a1z = i1z - oz;
        const bool ok = (a0x >= 0) & (a1x < ex) &
                        (a0y >= 0) & (a1y < ey) &
                        (a0z >= 0) & (a1z < ez);

        float2 c000, c001, c010, c011, c100, c101, c110, c111;
        if (ok) {   // common path: 8 LDS reads
            const int r00 = (a0x * RH + a0y) * RWP;
            const int r01 = (a0x * RH + a1y) * RWP;
            const int r10 = (a1x * RH + a0y) * RWP;
            const int r11 = (a1x * RH + a1y) * RWP;
            c000 = sv[r00 + a0z];  c001 = sv[r00 + a1z];
            c010 = sv[r01 + a0z];  c011 = sv[r01 + a1z];
            c100 = sv[r10 + a0z];  c101 = sv[r10 + a1z];
            c110 = sv[r11 + a0z];  c111 = sv[r11 + a1z];
        } else {    // rare (~2e-4/voxel): exact global gather, same indices
            const int rx0 = i0x * HW, rx1 = i1x * HW;
            const int ry0 = i0y * Ww, ry1 = i1y * Ww;
            c000 = v2[rx0 + ry0 + i0z];  c001 = v2[rx0 + ry0 + i1z];
            c010 = v2[rx0 + ry1 + i0z];  c011 = v2[rx0 + ry1 + i1z];
            c100 = v2[rx1 + ry0 + i0z];  c101 = v2[rx1 + ry0 + i1z];
            c110 = v2[rx1 + ry1 + i0z];  c111 = v2[rx1 + ry1 + i1z];
        }

        // corner bit 0 -> lower index, weight d1; bit 1 -> upper, weight d0
        const float w000 = d1x * d1y * d1z;
        const float w001 = d1x * d1y * d0z;
        const float w010 = d1x * d0y * d1z;
        const float w011 = d1x * d0y * d0z;
        const float w100 = d0x * d1y * d1z;
        const float w101 = d0x * d1y * d0z;
        const float w110 = d0x * d0y * d1z;
        const float w111 = d0x * d0y * d0z;

        float oxv = w000 * c000.x;
        float oyv = w000 * c000.y;
        oxv = fmaf(w001, c001.x, oxv);  oyv = fmaf(w001, c001.y, oyv);
        oxv = fmaf(w010, c010.x, oxv);  oyv = fmaf(w010, c010.y, oyv);
        oxv = fmaf(w011, c011.x, oxv);  oyv = fmaf(w011, c011.y, oyv);
        oxv = fmaf(w100, c100.x, oxv);  oyv = fmaf(w100, c100.y, oyv);
        oxv = fmaf(w101, c101.x, oxv);  oyv = fmaf(w101, c101.y, oyv);
        oxv = fmaf(w110, c110.x, oxv);  oyv = fmaf(w110, c110.y, oyv);
        oxv = fmaf(w111, c111.x, oxv);  oyv = fmaf(w111, c111.y, oyv);

        reinterpret_cast<float2*>(out)[gcur] = make_float2(oxv, oyv);

        fx = nfx;  fy = nfy;  fz = nfz;
        gidx += HW;
    }
}

extern "C" void kernel_launch(void* const* d_in, const int* in_sizes, int n_in,
                              void* d_out, int out_size, void* d_ws, size_t ws_size,
                              hipStream_t stream)
{
    const float* vol  = (const float*)d_in[0];   // [2,160,192,160,2] f32
    const float* flow = (const float*)d_in[1];   // [2,160,192,160,3] f32
    float* out = (float*)d_out;                  // [2,160,192,160,2] f32

    SpatialTransformer_44418551776013_kernel<<<NBLK, 256, LDS_BYTES, stream>>>(vol, flow, out);
}